// Round 5
// baseline (698.405 us; speedup 1.0000x reference)
//
#include <hip/hip_runtime.h>
#include <hip/hip_bf16.h>
#include <hip/hip_math_constants.h>

// Problem dims (fixed by setup_inputs): L=2, B=32, S=2048, D=1024. All floats f32.
constexpr int LAY = 2;
constexpr int BB  = 32;
constexpr int SS  = 2048;
constexpr int DD  = 1024;

typedef unsigned short u16;
typedef short  short8  __attribute__((ext_vector_type(8)));
typedef u16    u16x8   __attribute__((ext_vector_type(8)));
typedef float  floatx4 __attribute__((ext_vector_type(4)));

__device__ inline float bf2f(u16 u) {
    union { unsigned int i; float f; } v; v.i = ((unsigned int)u) << 16; return v.f;
}
__device__ inline u16 f2bf_rn(float f) {
    union { float f; unsigned int i; } v; v.f = f;
    unsigned int x = v.i;
    return (u16)((x + 0x7FFFu + ((x >> 16) & 1u)) >> 16);
}

// tanh(x) = 1 - 2/(1+e^{2x}); saturates to +/-1 at large |x|, no NaN.
__device__ __forceinline__ float fast_tanh(float x) {
    float e = __expf(2.0f * x);
    return 1.0f - 2.0f * __frcp_rn(1.0f + e);
}

__device__ __forceinline__ void gload_lds16(const u16* g, u16* l) {
    __builtin_amdgcn_global_load_lds(
        (const __attribute__((address_space(1))) void*)g,
        (__attribute__((address_space(3))) void*)l, 16, 0, 0);
}

// ---------------------------------------------------------------------------
// enc f32 -> bf16 (rn). Grid-stride: 2048 blocks x 256 thr x 16 iters x 8 elems.
__global__ __launch_bounds__(256) void convert_enc(const float* __restrict__ enc,
                                                   u16* __restrict__ encbf) {
    size_t gid = (size_t)blockIdx.x * 256 + threadIdx.x;   // 0..524287
    #pragma unroll 4
    for (int it = 0; it < 16; ++it) {
        size_t i = (it * 524288ull + gid) * 8;
        floatx4 v0 = *reinterpret_cast<const floatx4*>(enc + i);
        floatx4 v1 = *reinterpret_cast<const floatx4*>(enc + i + 4);
        u16x8 r;
        #pragma unroll
        for (int j = 0; j < 4; ++j) { r[j] = f2bf_rn(v0[j]); r[4 + j] = f2bf_rn(v1[j]); }
        *reinterpret_cast<u16x8*>(encbf + i) = r;
    }
}

// W_enc f32 [K][N] -> wT bf16 [N][K]. Thread handles (n, 8 consecutive k).
__global__ __launch_bounds__(256) void transpose_wenc(const float* __restrict__ W,
                                                      u16* __restrict__ wT) {
    int gid = blockIdx.x * 256 + threadIdx.x;   // 0..131071
    int n = gid & 1023, c = gid >> 10;          // c: 0..127
    int k0 = c * 8;
    u16x8 r;
    #pragma unroll
    for (int j = 0; j < 8; ++j) r[j] = f2bf_rn(W[(size_t)(k0 + j) * DD + n]);
    *reinterpret_cast<u16x8*>(&wT[(size_t)n * DD + k0]) = r;
}

// ---------------------------------------------------------------------------
// dec_proj[b][col] += sum_{e in kc-chunk} h[e] * W_dec[e][col]  (+b_dec on kc==0)
__global__ __launch_bounds__(256) void dec_proj_kernel(
    const float* __restrict__ dec_hidden, const float* __restrict__ W_dec,
    const float* __restrict__ b_dec, float* __restrict__ dec_proj) {
    int kc = blockIdx.x, cb = blockIdx.y, b = blockIdx.z, t = threadIdx.x;
    int col = cb * 256 + t;
    const float* h = dec_hidden + (LAY - 1) * BB * DD + b * DD + kc * 256;
    const float* Wp = W_dec + (size_t)kc * 256 * DD + col;
    float a0 = 0.f, a1 = 0.f, a2 = 0.f, a3 = 0.f;
    for (int e = 0; e < 256; e += 4) {
        a0 += h[e + 0] * Wp[(size_t)(e + 0) * DD];
        a1 += h[e + 1] * Wp[(size_t)(e + 1) * DD];
        a2 += h[e + 2] * Wp[(size_t)(e + 2) * DD];
        a3 += h[e + 3] * Wp[(size_t)(e + 3) * DD];
    }
    float v = (a0 + a1) + (a2 + a3);
    if (kc == 0) v += b_dec[col];
    atomicAdd(&dec_proj[b * DD + col], v);
}

// ---------------------------------------------------------------------------
// Fused: E = enc @ W_enc;  scores[r] += sum_n tanh(E[r][n] + dec_proj[b][n] + b_enc[n]) * w_att[n]
// 128x128 tile, BK=64, global_load_lds width-16 staging, XOR-swizzled LDS
// (conflict-free, verified r4: SQ_LDS_BANK_CONFLICT=0).
// XCD-aware flat grid: xcd = flat&7; the 8 bn-siblings sharing an A-strip are
// spaced by 8 in flat id -> same XCD -> A-strip fetched once per XCD L2.
__global__ __launch_bounds__(256) void score_gemm_bf(
    const u16* __restrict__ enc,      // [M][K] bf16 row-major
    const u16* __restrict__ wT,       // [N][K] bf16 row-major
    const float* __restrict__ dec_proj,
    const float* __restrict__ b_enc, const float* __restrict__ w_att,
    float* __restrict__ scores) {
    __shared__ u16 As[128 * 64];
    __shared__ u16 Bs[128 * 64];

    const int flat = blockIdx.x;           // 0..4095
    const int xcd  = flat & 7;
    const int bm   = xcd * 64 + (flat >> 6);      // 0..511
    const int bn   = (flat >> 3) & 7;             // 0..7
    const int row0 = bm * 128, col0 = bn * 128;

    const int tid  = threadIdx.x;
    const int lane = tid & 63, w = tid >> 6;
    const int wm   = w >> 1,  wn = w & 1;
    const int quad = lane >> 4, l16 = lane & 15;

    // staging: wave w, issue i covers rows [i*32 + w*8, +8)
    // lane l -> local row l>>3, LDS kchunk slot l&7, global kchunk (l&7)^(l>>3)
    const int srow = w * 8 + (lane >> 3);
    const int scol = (((lane & 7) ^ (lane >> 3)) * 8);

    floatx4 acc[4][4];
    #pragma unroll
    for (int i = 0; i < 4; ++i)
        #pragma unroll
        for (int j = 0; j < 4; ++j)
            acc[i][j] = (floatx4){0.f, 0.f, 0.f, 0.f};

    for (int kt = 0; kt < DD / 64; ++kt) {
        const int k0 = kt * 64;
        __syncthreads();   // prev MFMA reads done before LDS overwrite
        #pragma unroll
        for (int i = 0; i < 4; ++i) {
            gload_lds16(&enc[(size_t)(row0 + i * 32 + srow) * DD + k0 + scol],
                        &As[(i * 32 + w * 8) * 64]);
            gload_lds16(&wT [(size_t)(col0 + i * 32 + srow) * DD + k0 + scol],
                        &Bs[(i * 32 + w * 8) * 64]);
        }
        __syncthreads();   // drains vmcnt (DMA complete) + barrier
        #pragma unroll
        for (int ks = 0; ks < 2; ++ks) {
            short8 a[4], b[4];
            #pragma unroll
            for (int tm = 0; tm < 4; ++tm) {
                int r = wm * 64 + tm * 16 + l16;
                int kcs = (ks * 4 + quad) ^ (l16 & 7);
                a[tm] = *reinterpret_cast<const short8*>(&As[r * 64 + kcs * 8]);
            }
            #pragma unroll
            for (int tn = 0; tn < 4; ++tn) {
                int r = wn * 64 + tn * 16 + l16;
                int kcs = (ks * 4 + quad) ^ (l16 & 7);
                b[tn] = *reinterpret_cast<const short8*>(&Bs[r * 64 + kcs * 8]);
            }
            #pragma unroll
            for (int tm = 0; tm < 4; ++tm)
                #pragma unroll
                for (int tn = 0; tn < 4; ++tn)
                    acc[tm][tn] = __builtin_amdgcn_mfma_f32_16x16x32_bf16(
                        a[tm], b[tn], acc[tm][tn], 0, 0, 0);
        }
    }

    // Epilogue: fast tanh + dot(w_att) + per-row reduce + atomicAdd
    // C/D layout (m89/m91-verified): col = lane&15, row = quad*4 + reg
    const int bIdx = row0 / SS;
    const float* dp = dec_proj + bIdx * DD;
    float cvec[4], wvv[4];
    #pragma unroll
    for (int tn = 0; tn < 4; ++tn) {
        int n = col0 + wn * 64 + tn * 16 + l16;
        cvec[tn] = dp[n] + b_enc[n];
        wvv[tn]  = w_att[n];
    }
    #pragma unroll
    for (int tm = 0; tm < 4; ++tm) {
        float rs0 = 0.f, rs1 = 0.f, rs2 = 0.f, rs3 = 0.f;
        #pragma unroll
        for (int tn = 0; tn < 4; ++tn) {
            rs0 += fast_tanh(acc[tm][tn][0] + cvec[tn]) * wvv[tn];
            rs1 += fast_tanh(acc[tm][tn][1] + cvec[tn]) * wvv[tn];
            rs2 += fast_tanh(acc[tm][tn][2] + cvec[tn]) * wvv[tn];
            rs3 += fast_tanh(acc[tm][tn][3] + cvec[tn]) * wvv[tn];
        }
        #pragma unroll
        for (int off = 1; off < 16; off <<= 1) {
            rs0 += __shfl_xor(rs0, off, 64);
            rs1 += __shfl_xor(rs1, off, 64);
            rs2 += __shfl_xor(rs2, off, 64);
            rs3 += __shfl_xor(rs3, off, 64);
        }
        if (l16 == 0) {
            int rbase = row0 + wm * 64 + tm * 16 + quad * 4;
            atomicAdd(&scores[rbase + 0], rs0);
            atomicAdd(&scores[rbase + 1], rs1);
            atomicAdd(&scores[rbase + 2], rs2);
            atomicAdd(&scores[rbase + 3], rs3);
        }
    }
}

// ---------------------------------------------------------------------------
// Masked softmax over S per b. b_att omitted (shift-invariant).
__global__ __launch_bounds__(256) void softmax_kernel(
    const float* __restrict__ scores, const int* __restrict__ mask,
    float* __restrict__ attn_out) {
    int b = blockIdx.x, t = threadIdx.x;
    const float* srow = scores + b * SS;
    const int*   mrow = mask + b * SS;
    float vals[8];
    float vmax = -1e30f;
    #pragma unroll
    for (int i = 0; i < 8; ++i) {
        int s = i * 256 + t;
        float v = (mrow[s] == 0) ? -1e10f : srow[s];
        vals[i] = v;
        vmax = fmaxf(vmax, v);
    }
    #pragma unroll
    for (int off = 32; off >= 1; off >>= 1) vmax = fmaxf(vmax, __shfl_xor(vmax, off, 64));
    __shared__ float sm[4];
    if ((t & 63) == 0) sm[t >> 6] = vmax;
    __syncthreads();
    vmax = fmaxf(fmaxf(sm[0], sm[1]), fmaxf(sm[2], sm[3]));
    float sum = 0.f;
    #pragma unroll
    for (int i = 0; i < 8; ++i) { vals[i] = __expf(vals[i] - vmax); sum += vals[i]; }
    #pragma unroll
    for (int off = 32; off >= 1; off >>= 1) sum += __shfl_xor(sum, off, 64);
    __shared__ float ssum[4];
    if ((t & 63) == 0) ssum[t >> 6] = sum;
    __syncthreads();
    sum = ssum[0] + ssum[1] + ssum[2] + ssum[3];
    float inv = 1.f / sum;
    #pragma unroll
    for (int i = 0; i < 8; ++i) attn_out[b * SS + i * 256 + t] = vals[i] * inv;
}

// ---------------------------------------------------------------------------
// ctx[b][d..d+3] += sum_s attn[b][s] * encbf[b][s][d..d+3]
__global__ __launch_bounds__(256) void context_bf(
    const float* __restrict__ attn, const u16* __restrict__ encbf,
    float* __restrict__ ctx) {
    int scb = blockIdx.x;   // 0..7
    int b   = blockIdx.y;   // 0..31
    int d = threadIdx.x * 4;
    const u16*  base = encbf + ((size_t)b * SS + scb * 256) * DD + d;
    const float* ar  = attn + b * SS + scb * 256;
    float a0 = 0.f, a1 = 0.f, a2 = 0.f, a3 = 0.f;
    #pragma unroll 4
    for (int s = 0; s < 256; ++s) {
        unsigned long long v = *reinterpret_cast<const unsigned long long*>(base + (size_t)s * DD);
        float w = ar[s];
        a0 += w * bf2f((u16)(v       & 0xFFFF));
        a1 += w * bf2f((u16)((v >> 16) & 0xFFFF));
        a2 += w * bf2f((u16)((v >> 32) & 0xFFFF));
        a3 += w * bf2f((u16)((v >> 48) & 0xFFFF));
    }
    atomicAdd(&ctx[b * DD + d + 0], a0);
    atomicAdd(&ctx[b * DD + d + 1], a1);
    atomicAdd(&ctx[b * DD + d + 2], a2);
    atomicAdd(&ctx[b * DD + d + 3], a3);
}

// ---------------------------------------------------------------------------
extern "C" void kernel_launch(void* const* d_in, const int* in_sizes, int n_in,
                              void* d_out, int out_size, void* d_ws, size_t ws_size,
                              hipStream_t stream) {
    const float* dec_hidden = (const float*)d_in[0];
    const float* enc        = (const float*)d_in[1];
    const int*   mask       = (const int*)d_in[2];
    const float* W_dec      = (const float*)d_in[3];
    const float* b_dec      = (const float*)d_in[4];
    const float* W_enc      = (const float*)d_in[5];
    const float* b_enc      = (const float*)d_in[6];
    const float* w_att      = (const float*)d_in[7];
    // d_in[8] (b_att): uniform shift into softmax -> no effect, omitted.

    float* out = (float*)d_out;               // [0,32768) context ; [32768,98304) attn
    float* ws  = (float*)d_ws;
    float* dec_proj = ws;                     // 32768 f32
    float* scores   = ws + 32768;             // 65536 f32
    u16*   wT       = (u16*)(ws + 98304);     // 1M bf16 (2 MB)
    u16*   encbf    = (u16*)(ws + 622592);    // 64M bf16 (128 MB)
    float* attn     = out + 32768;

    hipMemsetAsync(ws, 0, 98304 * sizeof(float), stream);    // dec_proj + scores
    hipMemsetAsync(out, 0, 32768 * sizeof(float), stream);   // context accumulator

    convert_enc<<<2048, 256, 0, stream>>>(enc, encbf);
    transpose_wenc<<<512, 256, 0, stream>>>(W_enc, wT);
    dec_proj_kernel<<<dim3(4, 4, 32), 256, 0, stream>>>(dec_hidden, W_dec, b_dec, dec_proj);
    score_gemm_bf<<<4096, 256, 0, stream>>>(encbf, wT, dec_proj, b_enc, w_att, scores);
    softmax_kernel<<<32, 256, 0, stream>>>(scores, mask, attn);
    context_bf<<<dim3(8, 32), 256, 0, stream>>>(attn, encbf, out);
}